// Round 1
// baseline (1537.461 us; speedup 1.0000x reference)
//
#include <hip/hip_runtime.h>

// LiquidNN LTC: B=512, S=512, D=H=128, O=1, UNFOLDS=6, dt=0.1, tau=1.
// One block per batch row (grid=512, block=256, 2 blocks/CU).
// Thread t: output o = t>>1, K-half kh = t&1 (64 MACs -> 32 v_dot2_f32_f16).
// W_in/W_r rows register-resident as f16x2. h fp32 in registers (authoritative),
// f16 copy in double-buffered LDS for the matvec broadcast.

typedef _Float16 v2h __attribute__((ext_vector_type(2)));

#define S_LEN 512
#define HDIM 128
#define NUNF 6
#define DTC 0.1f

__device__ __forceinline__ float fast_tanh(float y) {
    // tanh(y) = 1 - 2/(e^{2y}+1); v_exp/v_rcp based, NaN-free at +-inf
    float u = __expf(2.0f * y);
    return 1.0f - __fdividef(2.0f, u + 1.0f);
}

__global__ __launch_bounds__(256, 2)
void ltc_kernel(const float* __restrict__ x,
                const float* __restrict__ W_in,
                const float* __restrict__ b_in,
                const float* __restrict__ W_r,
                const float* __restrict__ b_r,
                const float* __restrict__ W_fc,
                const float* __restrict__ b_fc,
                float* __restrict__ out)
{
    const int b     = blockIdx.x;
    const int tid   = threadIdx.x;   // 0..255
    const int o     = tid >> 1;      // 0..127
    const int kh    = tid & 1;       // K-half
    const int kbase = kh * 64;       // element offset into K

    __shared__ __align__(16) _Float16 hbuf[2][HDIM];
    __shared__ __align__(16) _Float16 xbuf[2][HDIM];
    __shared__ float red[4];

    // ---- one-time: weight rows into registers as f16 pairs (32+32 VGPRs) ----
    v2h wr[32], wi[32];
    {
        const float4* wrp = reinterpret_cast<const float4*>(W_r  + o * HDIM + kbase);
        const float4* wip = reinterpret_cast<const float4*>(W_in + o * HDIM + kbase);
#pragma unroll
        for (int j = 0; j < 16; ++j) {
            float4 f = wrp[j];
            wr[2*j]   = v2h{(_Float16)f.x, (_Float16)f.y};
            wr[2*j+1] = v2h{(_Float16)f.z, (_Float16)f.w};
            float4 g = wip[j];
            wi[2*j]   = v2h{(_Float16)g.x, (_Float16)g.y};
            wi[2*j+1] = v2h{(_Float16)g.z, (_Float16)g.w};
        }
    }
    const float binv = b_in[o];
    const float brv  = b_r[o];

    const float* x_row = x + (size_t)b * S_LEN * HDIM;

    float h_o = 0.0f;   // fp32 authoritative h (identical on lane pair)

    // prologue: stage x[b,0,:], zero h LDS copy
    if (tid < HDIM) {
        xbuf[0][tid] = (_Float16)x_row[tid];
        hbuf[0][tid] = (_Float16)0.0f;
    }
    __syncthreads();

    for (int s = 0; s < S_LEN; ++s) {
        // prefetch next step's x into registers (HBM latency hidden by ~1500 cyc step)
        float xnext = 0.0f;
        if (tid < HDIM && s + 1 < S_LEN)
            xnext = x_row[(size_t)(s + 1) * HDIM + tid];

        // ---- input map: xin_o = x[b,s,:].W_in[o,:] + b_in[o] ----
        float xin_o;
        {
            const float4* hp = reinterpret_cast<const float4*>(&xbuf[s & 1][kbase]);
            float4 hv[8];
#pragma unroll
            for (int j = 0; j < 8; ++j) hv[j] = hp[j];
            const v2h* hh = reinterpret_cast<const v2h*>(hv);
            float a0 = 0.f, a1 = 0.f, a2 = 0.f, a3 = 0.f;
#pragma unroll
            for (int j = 0; j < 32; j += 4) {
                a0 = __builtin_amdgcn_fdot2(wi[j],   hh[j],   a0, false);
                a1 = __builtin_amdgcn_fdot2(wi[j+1], hh[j+1], a1, false);
                a2 = __builtin_amdgcn_fdot2(wi[j+2], hh[j+2], a2, false);
                a3 = __builtin_amdgcn_fdot2(wi[j+3], hh[j+3], a3, false);
            }
            float sum = (a0 + a1) + (a2 + a3);
            sum += __shfl_xor(sum, 1);
            xin_o = sum + binv;  // identical on both lanes of the pair
        }

        // ---- 6 ODE unfolds ----
#pragma unroll
        for (int u = 0; u < NUNF; ++u) {
            const float4* hp = reinterpret_cast<const float4*>(&hbuf[u & 1][kbase]);
            float4 hv[8];
#pragma unroll
            for (int j = 0; j < 8; ++j) hv[j] = hp[j];
            const v2h* hh = reinterpret_cast<const v2h*>(hv);
            float a0 = 0.f, a1 = 0.f, a2 = 0.f, a3 = 0.f;
#pragma unroll
            for (int j = 0; j < 32; j += 4) {
                a0 = __builtin_amdgcn_fdot2(wr[j],   hh[j],   a0, false);
                a1 = __builtin_amdgcn_fdot2(wr[j+1], hh[j+1], a1, false);
                a2 = __builtin_amdgcn_fdot2(wr[j+2], hh[j+2], a2, false);
                a3 = __builtin_amdgcn_fdot2(wr[j+3], hh[j+3], a3, false);
            }
            float sum = (a0 + a1) + (a2 + a3);
            sum += __shfl_xor(sum, 1);
            float yv = xin_o + brv + sum;
            float v  = fast_tanh(yv);
            h_o = h_o + DTC * (v - h_o);           // tau=1: h += dt*(-h+v)
            if ((tid & 1) == 0)
                hbuf[(u + 1) & 1][o] = (_Float16)h_o;
            if (u == NUNF - 1 && tid < HDIM && s + 1 < S_LEN)
                xbuf[(s + 1) & 1][tid] = (_Float16)xnext;
            __syncthreads();
        }
    }

    // ---- epilogue: out[b] = h . W_fc[0,:] + b_fc ----
    float partial = 0.0f;
    if ((tid & 1) == 0) partial = h_o * W_fc[o];
#pragma unroll
    for (int d = 1; d < 64; d <<= 1) partial += __shfl_xor(partial, d);
    if ((tid & 63) == 0) red[tid >> 6] = partial;
    __syncthreads();
    if (tid == 0) out[b] = red[0] + red[1] + red[2] + red[3] + b_fc[0];
}

extern "C" void kernel_launch(void* const* d_in, const int* in_sizes, int n_in,
                              void* d_out, int out_size, void* d_ws, size_t ws_size,
                              hipStream_t stream) {
    const float* x    = (const float*)d_in[0];
    const float* W_in = (const float*)d_in[1];
    const float* b_in = (const float*)d_in[2];
    const float* W_r  = (const float*)d_in[3];
    const float* b_r  = (const float*)d_in[4];
    const float* W_fc = (const float*)d_in[5];
    const float* b_fc = (const float*)d_in[6];
    float* outp = (float*)d_out;
    (void)in_sizes; (void)n_in; (void)out_size; (void)d_ws; (void)ws_size;
    ltc_kernel<<<dim3(512), dim3(256), 0, stream>>>(x, W_in, b_in, W_r, b_r, W_fc, b_fc, outp);
}